// Round 4
// baseline (296.160 us; speedup 1.0000x reference)
//
#include <hip/hip_runtime.h>

#define N_BATCH   50000
#define N_FEATURE 128
#define DEPTH     9
#define N_TREE    200
#define N_NODE    1023
#define N_OUTPUT  8

#define BPB     64                            // batches per block (lanes)
#define BLOCK   256                           // 4 waves
#define NCHUNK  ((N_BATCH + BPB - 1) / BPB)   // 782
#define TPR     8                             // trees per round (2 per wave)
#define ROUNDS  (N_TREE / TPR)                // 25

// per-round staged block (contiguous, built by pack_kernel in ws):
//   thL [TPR][256] f32 : 8192 @ 0       (threshold of left child of parent n)
//   thR [TPR][256] f32 : 8192 @ 8192
//   fp  [TPR][256] u16 : 4096 @ 16384   (feat_l | feat_r<<8)
//   rootTh [TPR] f32   :   32 @ 20480
//   rootF  [TPR] i32   :   32 @ 20512
#define RB_BYTES 20544
#define RB_F4    (RB_BYTES / 16)              // 1284
#define WS_NEED  ((size_t)ROUNDS * RB_BYTES)  // 513600

__global__ void pack_kernel(const int* __restrict__ feature,
                            const float* __restrict__ threshold,
                            char* __restrict__ ws) {
    int id = blockIdx.x * 256 + threadIdx.x;       // 200*256
    if (id >= N_TREE * 256) return;
    int t = id >> 8, n = id & 255;
    int r = t / TPR, tl = t % TPR;
    char* rb = ws + (size_t)r * RB_BYTES;
    float* thL = (float*)rb;
    float* thR = (float*)(rb + 8192);
    unsigned short* fp = (unsigned short*)(rb + 16384);
    float* rootTh = (float*)(rb + 20480);
    int*   rootF  = (int*)(rb + 20512);
    if (n < 255) {                                  // pair for parent n: children 2n+1, 2n+2
        int gi = t * N_NODE + 2 * n + 1;
        thL[tl * 256 + n] = threshold[gi];
        thR[tl * 256 + n] = threshold[gi + 1];
        fp[tl * 256 + n]  = (unsigned short)((feature[gi] & 255) | ((feature[gi + 1] & 255) << 8));
    } else {                                        // unused slot; write roots instead
        thL[tl * 256 + 255] = 0.f;
        thR[tl * 256 + 255] = 0.f;
        fp[tl * 256 + 255]  = 0;
        rootTh[tl] = threshold[t * N_NODE];
        rootF[tl]  = feature[t * N_NODE];
    }
}

template<bool PACKED>
__global__ __launch_bounds__(BLOCK, 3)
void tree_kernel(const float* __restrict__ x,
                 const int*   __restrict__ feature,
                 const float* __restrict__ threshold,
                 const char*  __restrict__ ws,
                 const float* __restrict__ value,
                 float*       __restrict__ out)
{
    __shared__ float xt[N_FEATURE * BPB];            // 32 KB, xt[f*64+b]: gather bank = lane%32 (free)
    __shared__ __align__(16) char recbuf[RB_BYTES];  // 20544 B staged records (aliased by transpose/reduction)

    float* thL = (float*)recbuf;
    float* thR = (float*)(recbuf + 8192);
    unsigned short* fp = (unsigned short*)(recbuf + 16384);
    float* rootTh = (float*)(recbuf + 20480);
    int*   rootF  = (int*)(recbuf + 20512);

    const int tid   = threadIdx.x;
    const int chunk = blockIdx.x;
    const int b     = tid & 63;
    const int g     = tid >> 6;

    // ---- round-0 record prefetch (in flight during transpose) ----
    float4 pf[6];
    float thLr[8], thRr[8]; int fpr[8]; float rootThR = 0.f; int rootFR = 0;
    if (PACKED) {
        const float4* src = (const float4*)ws;
        #pragma unroll
        for (int k = 0; k < 6; ++k) {
            int idx = k * 256 + tid;
            if (idx < RB_F4) pf[k] = src[idx];
        }
    } else {
        #pragma unroll
        for (int j = 0; j < 8; ++j) {
            int s = j * 256 + tid, tl = s >> 8, n = s & 255;
            int t = tl;                                // round 0
            if (n < 255) {
                int gi = t * N_NODE + 2 * n + 1;
                thLr[j] = threshold[gi]; thRr[j] = threshold[gi + 1];
                fpr[j]  = (feature[gi] & 255) | ((feature[gi + 1] & 255) << 8);
            } else { thLr[j] = 0.f; thRr[j] = 0.f; fpr[j] = 0; }
        }
        if (tid < TPR) { rootThR = threshold[tid * N_NODE]; rootFR = feature[tid * N_NODE]; }
    }

    // ---- stage x chunk transposed into LDS (conflict-free via XOR-swizzled R) ----
    {
        const float4* x4 = (const float4*)x;
        float4* R = (float4*)recbuf;                 // 16 KB alias (pre-round-0 only)
        #pragma unroll
        for (int rr = 0; rr < 2; ++rr) {
            #pragma unroll
            for (int k = 0; k < 4; ++k) {
                int j  = tid + k * BLOCK;
                int bl = j >> 5, f4 = j & 31;
                int gb = chunk * BPB + rr * 32 + bl;
                float4 v = (gb < N_BATCH) ? x4[(size_t)gb * 32 + f4]
                                          : make_float4(0.f, 0.f, 0.f, 0.f);
                R[bl * 32 + (f4 ^ bl)] = v;
            }
            __syncthreads();
            {
                int b32 = tid & 31, fc = tid >> 5;
                int bb = rr * 32 + b32;
                #pragma unroll
                for (int c = 0; c < 4; ++c) {
                    int f4 = fc * 4 + c;
                    float4 v = R[b32 * 32 + (f4 ^ b32)];
                    xt[(f4 * 4 + 0) * BPB + bb] = v.x;
                    xt[(f4 * 4 + 1) * BPB + bb] = v.y;
                    xt[(f4 * 4 + 2) * BPB + bb] = v.z;
                    xt[(f4 * 4 + 3) * BPB + bb] = v.w;
                }
            }
            __syncthreads();
        }
    }

    float acc[N_OUTPUT];
    #pragma unroll
    for (int o = 0; o < N_OUTPUT; ++o) acc[o] = 0.f;

    for (int r = 0; r < ROUNDS; ++r) {
        __syncthreads();                             // recbuf free
        if (PACKED) {
            #pragma unroll
            for (int k = 0; k < 6; ++k) {
                int idx = k * 256 + tid;
                if (idx < RB_F4) ((float4*)recbuf)[idx] = pf[k];
            }
        } else {
            #pragma unroll
            for (int j = 0; j < 8; ++j) {
                int s = j * 256 + tid;
                thL[s] = thLr[j]; thR[s] = thRr[j]; fp[s] = (unsigned short)fpr[j];
            }
            if (tid < TPR) { rootTh[tid] = rootThR; rootF[tid] = rootFR; }
        }
        __syncthreads();                             // stage ready

        if (r + 1 < ROUNDS) {                        // prefetch next round
            if (PACKED) {
                const float4* src = (const float4*)(ws + (size_t)(r + 1) * RB_BYTES);
                #pragma unroll
                for (int k = 0; k < 6; ++k) {
                    int idx = k * 256 + tid;
                    if (idx < RB_F4) pf[k] = src[idx];
                }
            } else {
                #pragma unroll
                for (int j = 0; j < 8; ++j) {
                    int s = j * 256 + tid, tl = s >> 8, n = s & 255;
                    int t = (r + 1) * TPR + tl;
                    if (n < 255) {
                        int gi = t * N_NODE + 2 * n + 1;
                        thLr[j] = threshold[gi]; thRr[j] = threshold[gi + 1];
                        fpr[j]  = (feature[gi] & 255) | ((feature[gi + 1] & 255) << 8);
                    } else { thLr[j] = 0.f; thRr[j] = 0.f; fpr[j] = 0; }
                }
                if (tid < TPR) {
                    rootThR = threshold[((r + 1) * TPR + tid) * N_NODE];
                    rootFR  = feature[((r + 1) * TPR + tid) * N_NODE];
                }
            }
        }

        // ---- traverse 2 trees; record for next level always selected from regs ----
        int   n[2], fv[2], fpk[2];
        float th[2], cl[2], cr[2];
        #pragma unroll
        for (int u = 0; u < 2; ++u) {
            int tl = 2 * g + u;
            n[u]  = 0;
            th[u] = rootTh[tl];  fv[u] = rootF[tl];
            cl[u] = thL[tl * 256]; cr[u] = thR[tl * 256]; fpk[u] = fp[tl * 256];
        }
        #pragma unroll
        for (int d = 0; d < DEPTH; ++d) {
            #pragma unroll
            for (int u = 0; u < 2; ++u) {
                float xv = xt[fv[u] * BPB + b];              // the only on-chain LDS read
                int right = (xv > th[u]) ? 1 : 0;            // xval <= split -> left
                n[u] = 2 * n[u] + 1 + right;
                if (d < DEPTH - 1) {                         // select next record from regs
                    th[u] = right ? cr[u] : cl[u];
                    fv[u] = (fpk[u] >> (right << 3)) & 255;
                }
                if (d < DEPTH - 2) {                         // speculative pair read (n <= 254)
                    int base = (2 * g + u) * 256 + n[u];
                    cl[u] = thL[base]; cr[u] = thR[base]; fpk[u] = fp[base];
                }
            }
        }
        #pragma unroll
        for (int u = 0; u < 2; ++u) {
            int gt = r * TPR + 2 * g + u;
            const float4* vp = (const float4*)(value + ((size_t)gt * N_NODE + n[u]) * N_OUTPUT);
            float4 a0 = vp[0], a1 = vp[1];
            acc[0] += a0.x; acc[1] += a0.y; acc[2] += a0.z; acc[3] += a0.w;
            acc[4] += a1.x; acc[5] += a1.y; acc[6] += a1.z; acc[7] += a1.w;
        }
    }

    // ---- reduce 4 waves' partials (alias recbuf, stride-9 pad) ----
    __syncthreads();
    float* red = (float*)recbuf;                     // 4*576*4 = 9216 B
    {
        float* dst = red + (g * 576 + b * 9);
        #pragma unroll
        for (int o = 0; o < N_OUTPUT; ++o) dst[o] = acc[o];
    }
    __syncthreads();
    {
        int bl = tid >> 2, o0 = (tid & 3) * 2;
        int bg = chunk * BPB + bl;
        if (bg < N_BATCH) {
            float s0 = 0.f, s1 = 0.f;
            #pragma unroll
            for (int gg = 0; gg < 4; ++gg) {
                s0 += red[gg * 576 + bl * 9 + o0];
                s1 += red[gg * 576 + bl * 9 + o0 + 1];
            }
            float2 res;
            res.x = s0 * (1.0f / N_TREE);
            res.y = s1 * (1.0f / N_TREE);
            ((float2*)out)[(size_t)chunk * 256 + tid] = res;
        }
    }
}

extern "C" void kernel_launch(void* const* d_in, const int* in_sizes, int n_in,
                              void* d_out, int out_size, void* d_ws, size_t ws_size,
                              hipStream_t stream) {
    const float* x         = (const float*)d_in[0];
    const int*   feature   = (const int*)d_in[1];
    const float* threshold = (const float*)d_in[2];
    const float* value     = (const float*)d_in[5];   // children implied by complete heap layout
    float* out = (float*)d_out;

    if (ws_size >= WS_NEED) {
        char* ws = (char*)d_ws;
        pack_kernel<<<(N_TREE * 256 + 255) / 256, 256, 0, stream>>>(feature, threshold, ws);
        tree_kernel<true><<<dim3(NCHUNK), dim3(BLOCK), 0, stream>>>(x, feature, threshold, ws, value, out);
    } else {
        tree_kernel<false><<<dim3(NCHUNK), dim3(BLOCK), 0, stream>>>(x, feature, threshold, nullptr, value, out);
    }
}

// Round 5
// 254.935 us; speedup vs baseline: 1.1617x; 1.1617x over previous
//
#include <hip/hip_runtime.h>

#define N_BATCH   50000
#define N_FEATURE 128
#define DEPTH     9
#define N_TREE    200
#define N_NODE    1023
#define N_OUTPUT  8

#define BPB     64                            // batches per block (lanes)
#define BLOCK   256                           // 4 waves
#define NCHUNK  ((N_BATCH + BPB - 1) / BPB)   // 782
#define TPR     8                             // trees per round (2 per wave)
#define ROUNDS  (N_TREE / TPR)                // 25

// per-round staged block (contiguous, built by pack_kernel in ws), 20480 B:
//   pairS [TPR][256] float2 : 16384 @ 0     (thresholds of {left,right} child of parent n)
//   fpS   [TPR][256] u16    :  4096 @ 16384 (feat_l | feat_r<<8)
// slot n==255 is never a parent -> holds the root: pair.x = root th, fp low byte = root feat
#define RB_BYTES 20480
#define RB_F4    (RB_BYTES / 16)              // 1280 = 5 * 256  (uniform 5 float4/thread)
#define WS_NEED  ((size_t)ROUNDS * RB_BYTES)  // 512000

__global__ void pack_kernel(const int* __restrict__ feature,
                            const float* __restrict__ threshold,
                            char* __restrict__ ws) {
    int id = blockIdx.x * 256 + threadIdx.x;       // 200*256
    if (id >= N_TREE * 256) return;
    int t = id >> 8, n = id & 255;
    int r = t / TPR, tl = t % TPR;
    char* rb = ws + (size_t)r * RB_BYTES;
    float2* pairS = (float2*)rb;
    unsigned short* fpS = (unsigned short*)(rb + 16384);
    if (n < 255) {                                  // children 2n+1, 2n+2 (always internal)
        int gi = t * N_NODE + 2 * n + 1;
        pairS[tl * 256 + n] = make_float2(threshold[gi], threshold[gi + 1]);
        fpS[tl * 256 + n] = (unsigned short)((feature[gi] & 255) | ((feature[gi + 1] & 255) << 8));
    } else {                                        // root record in the spare slot
        pairS[tl * 256 + 255] = make_float2(threshold[t * N_NODE], 0.f);
        fpS[tl * 256 + 255] = (unsigned short)(feature[t * N_NODE] & 255);
    }
}

template<bool PACKED>
__global__ __launch_bounds__(BLOCK, 3)
void tree_kernel(const float* __restrict__ x,
                 const int*   __restrict__ feature,
                 const float* __restrict__ threshold,
                 const char*  __restrict__ ws,
                 const float* __restrict__ value,
                 float*       __restrict__ out)
{
    __shared__ float xt[N_FEATURE * BPB];            // 32 KB, xt[f*64+b]: gather bank = lane%32 (free)
    __shared__ __align__(16) char recbuf[RB_BYTES];  // 20480 B (aliased by transpose-R / reduction)

    float2* pairS = (float2*)recbuf;
    unsigned short* fpS = (unsigned short*)(recbuf + 16384);

    const int tid   = threadIdx.x;
    const int chunk = blockIdx.x;
    const int b     = tid & 63;
    const int g     = tid >> 6;

    // ---- round-0 record prefetch: uniform 5 float4/thread, NO guards (spill-safe) ----
    float4 pf[5];
    float2 pr[8]; unsigned short fr[8];              // fallback path regs
    if (PACKED) {
        const float4* src = (const float4*)ws;
        #pragma unroll
        for (int k = 0; k < 5; ++k) pf[k] = src[k * 256 + tid];
    } else {
        #pragma unroll
        for (int j = 0; j < 8; ++j) {
            int s = j * 256 + tid, t = s >> 8, n = s & 255;
            int gi   = (n < 255) ? (t * N_NODE + 2 * n + 1) : (t * N_NODE);
            int gi2  = (n < 255) ? (gi + 1) : gi;
            float a  = threshold[gi], c = threshold[gi2];
            int   fa = feature[gi] & 255, fc = feature[gi2] & 255;
            pr[j] = make_float2(a, (n < 255) ? c : 0.f);
            fr[j] = (unsigned short)((n < 255) ? (fa | (fc << 8)) : fa);
        }
    }

    // ---- stage x chunk transposed into LDS (conflict-free via XOR-swizzled R) ----
    {
        const float4* x4 = (const float4*)x;
        float4* R = (float4*)recbuf;                 // 16 KB alias (pre-round-0 only)
        #pragma unroll
        for (int rr = 0; rr < 2; ++rr) {
            #pragma unroll
            for (int k = 0; k < 4; ++k) {
                int j  = tid + k * BLOCK;
                int bl = j >> 5, f4 = j & 31;
                int gb = chunk * BPB + rr * 32 + bl;
                float4 v = (gb < N_BATCH) ? x4[(size_t)gb * 32 + f4]
                                          : make_float4(0.f, 0.f, 0.f, 0.f);
                R[bl * 32 + (f4 ^ bl)] = v;
            }
            __syncthreads();
            {
                int b32 = tid & 31, fc = tid >> 5;
                int bb = rr * 32 + b32;
                #pragma unroll
                for (int c = 0; c < 4; ++c) {
                    int f4 = fc * 4 + c;
                    float4 v = R[b32 * 32 + (f4 ^ b32)];
                    xt[(f4 * 4 + 0) * BPB + bb] = v.x;
                    xt[(f4 * 4 + 1) * BPB + bb] = v.y;
                    xt[(f4 * 4 + 2) * BPB + bb] = v.z;
                    xt[(f4 * 4 + 3) * BPB + bb] = v.w;
                }
            }
            __syncthreads();
        }
    }

    float acc[N_OUTPUT];
    #pragma unroll
    for (int o = 0; o < N_OUTPUT; ++o) acc[o] = 0.f;

    for (int r = 0; r < ROUNDS; ++r) {
        __syncthreads();                             // recbuf free
        if (PACKED) {
            #pragma unroll
            for (int k = 0; k < 5; ++k) ((float4*)recbuf)[k * 256 + tid] = pf[k];
        } else {
            #pragma unroll
            for (int j = 0; j < 8; ++j) {
                int s = j * 256 + tid;
                pairS[s] = pr[j]; fpS[s] = fr[j];
            }
        }
        __syncthreads();                             // stage ready

        if (r + 1 < ROUNDS) {                        // prefetch next round (unconditional)
            if (PACKED) {
                const float4* src = (const float4*)(ws + (size_t)(r + 1) * RB_BYTES);
                #pragma unroll
                for (int k = 0; k < 5; ++k) pf[k] = src[k * 256 + tid];
            } else {
                #pragma unroll
                for (int j = 0; j < 8; ++j) {
                    int s = j * 256 + tid, tl = s >> 8, n = s & 255;
                    int t = (r + 1) * TPR + tl;
                    int gi  = (n < 255) ? (t * N_NODE + 2 * n + 1) : (t * N_NODE);
                    int gi2 = (n < 255) ? (gi + 1) : gi;
                    float a  = threshold[gi], c = threshold[gi2];
                    int   fa = feature[gi] & 255, fc = feature[gi2] & 255;
                    pr[j] = make_float2(a, (n < 255) ? c : 0.f);
                    fr[j] = (unsigned short)((n < 255) ? (fa | (fc << 8)) : fa);
                }
            }
        }

        // ---- traverse 2 trees; next record always selected from regs (1 dep latency/level) ----
        int   n[2], fv[2], fpk[2];
        float th[2], cl[2], cr[2];
        #pragma unroll
        for (int u = 0; u < 2; ++u) {
            int tl = 2 * g + u;
            n[u] = 0;
            th[u] = pairS[tl * 256 + 255].x;         // root threshold
            fv[u] = fpS[tl * 256 + 255] & 255;       // root feature
            float2 c0 = pairS[tl * 256];             // children of root
            cl[u] = c0.x; cr[u] = c0.y; fpk[u] = fpS[tl * 256];
        }
        #pragma unroll
        for (int d = 0; d < DEPTH; ++d) {
            #pragma unroll
            for (int u = 0; u < 2; ++u) {
                float xv = xt[fv[u] * BPB + b];      // the only on-chain LDS read
                int right = (xv > th[u]) ? 1 : 0;    // xval <= split -> left
                n[u] = 2 * n[u] + 1 + right;
                if (d < DEPTH - 1) {                 // select next record from regs
                    th[u] = right ? cr[u] : cl[u];
                    fv[u] = (fpk[u] >> (right << 3)) & 255;
                }
                if (d < DEPTH - 2) {                 // speculative pair read (n <= 254 here)
                    int base = (2 * g + u) * 256 + n[u];
                    float2 p = pairS[base];          // one ds_read_b64
                    cl[u] = p.x; cr[u] = p.y; fpk[u] = fpS[base];
                }
            }
        }
        #pragma unroll
        for (int u = 0; u < 2; ++u) {
            int gt = r * TPR + 2 * g + u;
            const float4* vp = (const float4*)(value + ((size_t)gt * N_NODE + n[u]) * N_OUTPUT);
            float4 a0 = vp[0], a1 = vp[1];
            acc[0] += a0.x; acc[1] += a0.y; acc[2] += a0.z; acc[3] += a0.w;
            acc[4] += a1.x; acc[5] += a1.y; acc[6] += a1.z; acc[7] += a1.w;
        }
    }

    // ---- reduce 4 waves' partials (alias recbuf, stride-9 pad) ----
    __syncthreads();
    float* red = (float*)recbuf;                     // 4*576*4 = 9216 B
    {
        float* dst = red + (g * 576 + b * 9);
        #pragma unroll
        for (int o = 0; o < N_OUTPUT; ++o) dst[o] = acc[o];
    }
    __syncthreads();
    {
        int bl = tid >> 2, o0 = (tid & 3) * 2;
        int bg = chunk * BPB + bl;
        if (bg < N_BATCH) {
            float s0 = 0.f, s1 = 0.f;
            #pragma unroll
            for (int gg = 0; gg < 4; ++gg) {
                s0 += red[gg * 576 + bl * 9 + o0];
                s1 += red[gg * 576 + bl * 9 + o0 + 1];
            }
            float2 res;
            res.x = s0 * (1.0f / N_TREE);
            res.y = s1 * (1.0f / N_TREE);
            ((float2*)out)[(size_t)chunk * 256 + tid] = res;
        }
    }
}

extern "C" void kernel_launch(void* const* d_in, const int* in_sizes, int n_in,
                              void* d_out, int out_size, void* d_ws, size_t ws_size,
                              hipStream_t stream) {
    const float* x         = (const float*)d_in[0];
    const int*   feature   = (const int*)d_in[1];
    const float* threshold = (const float*)d_in[2];
    const float* value     = (const float*)d_in[5];   // children implied by complete heap layout
    float* out = (float*)d_out;

    if (ws_size >= WS_NEED) {
        char* ws = (char*)d_ws;
        pack_kernel<<<(N_TREE * 256 + 255) / 256, 256, 0, stream>>>(feature, threshold, ws);
        tree_kernel<true><<<dim3(NCHUNK), dim3(BLOCK), 0, stream>>>(x, feature, threshold, ws, value, out);
    } else {
        tree_kernel<false><<<dim3(NCHUNK), dim3(BLOCK), 0, stream>>>(x, feature, threshold, nullptr, value, out);
    }
}

// Round 6
// 200.488 us; speedup vs baseline: 1.4772x; 1.2716x over previous
//
#include <hip/hip_runtime.h>

#define N_BATCH   50000
#define N_FEATURE 128
#define DEPTH     9
#define N_TREE    200
#define N_NODE    1023
#define N_OUTPUT  8

#define BPB     64                            // batches per block (lanes)
#define BLOCK   256                           // 4 waves
#define NCHUNK  ((N_BATCH + BPB - 1) / BPB)   // 782
#define TPR     8                             // trees per round (2 per wave)
#define ROUNDS  (N_TREE / TPR)                // 25

// per-wave private record buffer (no cross-wave sharing -> no barriers):
//   per tree: pairTh[256] float2 (2048 B)  slot n = thresholds of {2n+1, 2n+2};
//             slot 255 = root threshold in .x
//             fpair [256] u16    (512 B)   slot n = feat(2n+1) | feat(2n+2)<<8;
//             slot 255 = root feature
#define TREE_B  2560
#define WAVE_B  (2 * TREE_B)                  // 5120
#define REC_B   (4 * WAVE_B)                  // 20480

__global__ __launch_bounds__(BLOCK, 3)
void tree_kernel(const float* __restrict__ x,
                 const int*   __restrict__ feature,
                 const float* __restrict__ threshold,
                 const float* __restrict__ value,
                 float*       __restrict__ out)
{
    __shared__ float xt[N_FEATURE * BPB];           // 32 KB, xt[f*64+b]: bank = lane%32 (free)
    __shared__ __align__(16) char recbuf[REC_B];    // 20 KB, partitioned per wave

    const int tid   = threadIdx.x;
    const int chunk = blockIdx.x;
    const int b     = tid & 63;                     // lane = batch within chunk
    const int g     = tid >> 6;                     // wave id: trees {2g, 2g+1} each round
    char* wbuf = recbuf + g * WAVE_B;

    // ---- prefetch round-0 records into regs (in flight during transpose) ----
    float thLr[8], thRr[8]; int fpr[8];
    #pragma unroll
    for (int j = 0; j < 8; ++j) {
        const int s = b + j * 64;                   // 512 slots / 64 lanes
        const int u = s >> 8, n = s & 255;
        const int gt  = 2 * g + u;                  // round 0
        const int gi  = (n < 255) ? (gt * N_NODE + 2 * n + 1) : (gt * N_NODE);
        const int gi2 = (n < 255) ? (gi + 1) : gi;
        thLr[j] = threshold[gi];
        thRr[j] = (n < 255) ? threshold[gi2] : 0.f;
        const int fa = feature[gi] & 255, fb = feature[gi2] & 255;
        fpr[j] = (n < 255) ? (fa | (fb << 8)) : fa;
    }

    // ---- stage x chunk transposed into LDS (conflict-free via XOR-swizzled R) ----
    {
        const float4* x4 = (const float4*)x;
        float4* R = (float4*)recbuf;                // 16 KB alias (pre-round-0 only)
        #pragma unroll
        for (int rr = 0; rr < 2; ++rr) {
            #pragma unroll
            for (int k = 0; k < 4; ++k) {
                const int j  = tid + k * BLOCK;
                const int bl = j >> 5, f4 = j & 31;
                const int gb = chunk * BPB + rr * 32 + bl;
                float4 v = (gb < N_BATCH) ? x4[(size_t)gb * 32 + f4]
                                          : make_float4(0.f, 0.f, 0.f, 0.f);
                R[bl * 32 + (f4 ^ bl)] = v;
            }
            __syncthreads();
            {
                const int b32 = tid & 31, fc = tid >> 5;
                const int bb = rr * 32 + b32;
                #pragma unroll
                for (int c = 0; c < 4; ++c) {
                    const int f4 = fc * 4 + c;
                    float4 v = R[b32 * 32 + (f4 ^ b32)];
                    xt[(f4 * 4 + 0) * BPB + bb] = v.x;
                    xt[(f4 * 4 + 1) * BPB + bb] = v.y;
                    xt[(f4 * 4 + 2) * BPB + bb] = v.z;
                    xt[(f4 * 4 + 3) * BPB + bb] = v.w;
                }
            }
            __syncthreads();
        }
    }
    // From here on: NO block barriers until the final reduction. Each wave
    // owns wbuf exclusively; ordering via its own lgkmcnt waits.

    float acc[N_OUTPUT];
    #pragma unroll
    for (int o = 0; o < N_OUTPUT; ++o) acc[o] = 0.f;

    float2*         pairT0 = (float2*)(wbuf);
    unsigned short* fp0    = (unsigned short*)(wbuf + 2048);
    float2*         pairT1 = (float2*)(wbuf + TREE_B);
    unsigned short* fp1    = (unsigned short*)(wbuf + TREE_B + 2048);

    for (int r = 0; r < ROUNDS; ++r) {
        // WAR: previous round's reads of wbuf must complete before overwrite
        __asm__ volatile("s_waitcnt lgkmcnt(0)" ::: "memory");
        #pragma unroll
        for (int j = 0; j < 8; ++j) {               // regs -> own LDS partition
            const int s = b + j * 64;
            const int u = s >> 8, n = s & 255;
            char* tb = wbuf + u * TREE_B;
            ((float2*)tb)[n] = make_float2(thLr[j], thRr[j]);
            ((unsigned short*)(tb + 2048))[n] = (unsigned short)fpr[j];
        }
        // RAW: cross-lane visibility of this wave's writes
        __asm__ volatile("s_waitcnt lgkmcnt(0)" ::: "memory");

        if (r + 1 < ROUNDS) {                       // prefetch next round (in flight below)
            #pragma unroll
            for (int j = 0; j < 8; ++j) {
                const int s = b + j * 64;
                const int u = s >> 8, n = s & 255;
                const int gt  = (r + 1) * TPR + 2 * g + u;
                const int gi  = (n < 255) ? (gt * N_NODE + 2 * n + 1) : (gt * N_NODE);
                const int gi2 = (n < 255) ? (gi + 1) : gi;
                thLr[j] = threshold[gi];
                thRr[j] = (n < 255) ? threshold[gi2] : 0.f;
                const int fa = feature[gi] & 255, fb = feature[gi2] & 255;
                fpr[j] = (n < 255) ? (fa | (fb << 8)) : fa;
            }
        }

        // ---- traverse 2 trees; next record selected from regs (1 LDS lat/level) ----
        int n0 = 0, n1 = 0;
        float th0 = pairT0[255].x, th1 = pairT1[255].x;    // roots
        int   fv0 = fp0[255] & 255, fv1 = fp1[255] & 255;
        float2 c0 = pairT0[0], c1 = pairT1[0];             // children of root
        int   k0 = fp0[0], k1 = fp1[0];
        #pragma unroll
        for (int d = 0; d < DEPTH; ++d) {
            const float xv0 = xt[fv0 * BPB + b];           // only on-chain LDS read
            const float xv1 = xt[fv1 * BPB + b];
            const int r0 = (xv0 > th0) ? 1 : 0;            // xval <= split -> left
            const int r1 = (xv1 > th1) ? 1 : 0;
            n0 = 2 * n0 + 1 + r0;
            n1 = 2 * n1 + 1 + r1;
            if (d < DEPTH - 1) {
                th0 = r0 ? c0.y : c0.x;  fv0 = (k0 >> (r0 << 3)) & 255;
                th1 = r1 ? c1.y : c1.x;  fv1 = (k1 >> (r1 << 3)) & 255;
            }
            if (d < DEPTH - 2) {                           // speculative pair read (n <= 254)
                c0 = pairT0[n0]; k0 = fp0[n0];
                c1 = pairT1[n1]; k1 = fp1[n1];
            }
        }
        {
            const int gt0 = r * TPR + 2 * g;
            const float4* v0 = (const float4*)(value + ((size_t)gt0 * N_NODE + n0) * N_OUTPUT);
            const float4* v1 = (const float4*)(value + ((size_t)(gt0 + 1) * N_NODE + n1) * N_OUTPUT);
            const float4 a0 = v0[0], a1 = v0[1];
            const float4 d0 = v1[0], d1 = v1[1];
            acc[0] += a0.x + d0.x;  acc[1] += a0.y + d0.y;
            acc[2] += a0.z + d0.z;  acc[3] += a0.w + d0.w;
            acc[4] += a1.x + d1.x;  acc[5] += a1.y + d1.y;
            acc[6] += a1.z + d1.z;  acc[7] += a1.w + d1.w;
        }
    }

    // ---- reduce 4 waves' partials (alias recbuf, stride-9 pad) ----
    __syncthreads();
    float* red = (float*)recbuf;                    // 4*576*4 = 9216 B <= 20480
    {
        float* dst = red + (g * 576 + b * 9);
        #pragma unroll
        for (int o = 0; o < N_OUTPUT; ++o) dst[o] = acc[o];
    }
    __syncthreads();
    {
        const int bl = tid >> 2, o0 = (tid & 3) * 2;
        const int bg = chunk * BPB + bl;
        if (bg < N_BATCH) {
            float s0 = 0.f, s1 = 0.f;
            #pragma unroll
            for (int gg = 0; gg < 4; ++gg) {
                s0 += red[gg * 576 + bl * 9 + o0];
                s1 += red[gg * 576 + bl * 9 + o0 + 1];
            }
            float2 res;
            res.x = s0 * (1.0f / N_TREE);
            res.y = s1 * (1.0f / N_TREE);
            ((float2*)out)[(size_t)chunk * 256 + tid] = res;   // coalesced, exactly once
        }
    }
}

extern "C" void kernel_launch(void* const* d_in, const int* in_sizes, int n_in,
                              void* d_out, int out_size, void* d_ws, size_t ws_size,
                              hipStream_t stream) {
    const float* x         = (const float*)d_in[0];
    const int*   feature   = (const int*)d_in[1];
    const float* threshold = (const float*)d_in[2];
    const float* value     = (const float*)d_in[5];   // children implied by complete heap layout
    float* out = (float*)d_out;

    // single launch, no workspace (harness poisons d_ws -> L2 pollution + evictions)
    tree_kernel<<<dim3(NCHUNK), dim3(BLOCK), 0, stream>>>(x, feature, threshold, value, out);
}

// Round 7
// 160.283 us; speedup vs baseline: 1.8477x; 1.2508x over previous
//
#include <hip/hip_runtime.h>

#define N_BATCH   50000
#define N_FEATURE 128
#define DEPTH     9
#define N_TREE    200
#define N_NODE    1023
#define N_OUTPUT  8

#define BPB     64                            // batches per block (lanes)
#define BLOCK   256                           // 4 waves
#define TPR     8                             // trees per round (2 per wave)
#define ROUNDS  (N_TREE / TPR)                // 25

// Grid decomposition: 782 chunks of 64 batches. 768 chunks = monolithic full
// blocks (3/CU * 256 CU slots, one clean phase). The 14 surplus chunks are
// shattered into 25 single-round blocks each so they backfill draining slots
// instead of forcing a second full phase (straggler tail = 2x elapsed).
#define FULL_CHUNKS 768
#define NCHUNK      ((N_BATCH + BPB - 1) / BPB)     // 782
#define TAIL_CHUNKS (NCHUNK - FULL_CHUNKS)          // 14
#define TAIL_SPLIT  ROUNDS                          // 1 round per tail block
#define TAIL_BLOCKS (TAIL_CHUNKS * TAIL_SPLIT)      // 350
#define GRID        (FULL_CHUNKS + TAIL_BLOCKS)     // 1118

// per-wave private record buffer (no cross-wave sharing -> no barriers):
//   per tree: pairTh[256] float2 (2048 B)  slot n = thresholds of {2n+1, 2n+2};
//             slot 255 = root threshold in .x
//             fpair [256] u16    (512 B)   slot n = feat(2n+1) | feat(2n+2)<<8;
//             slot 255 = root feature
#define TREE_B  2560
#define WAVE_B  (2 * TREE_B)                  // 5120
#define REC_B   (4 * WAVE_B)                  // 20480

__global__ __launch_bounds__(BLOCK, 3)
void tree_kernel(const float* __restrict__ x,
                 const int*   __restrict__ feature,
                 const float* __restrict__ threshold,
                 const float* __restrict__ value,
                 float*       __restrict__ out)
{
    __shared__ float xt[N_FEATURE * BPB];           // 32 KB, xt[f*64+b]: bank = lane%32 (free)
    __shared__ __align__(16) char recbuf[REC_B];    // 20 KB, partitioned per wave

    const int tid = threadIdx.x;
    const int bid = blockIdx.x;
    const int b   = tid & 63;                       // lane = batch within chunk
    const int g   = tid >> 6;                       // wave id: trees {2g, 2g+1} each round
    char* wbuf = recbuf + g * WAVE_B;

    // block-uniform work mapping (full monolith vs single-round tail shard)
    int chunk, r0, r1; bool tail;
    if (bid < FULL_CHUNKS) { chunk = bid; r0 = 0; r1 = ROUNDS; tail = false; }
    else {
        const int t2 = bid - FULL_CHUNKS;
        chunk = FULL_CHUNKS + t2 / TAIL_SPLIT;
        r0 = t2 % TAIL_SPLIT; r1 = r0 + 1; tail = true;
    }

    // ---- prefetch round-r0 records into regs (in flight during transpose) ----
    float thLr[8], thRr[8]; int fpr[8];
    #pragma unroll
    for (int j = 0; j < 8; ++j) {
        const int s = b + j * 64;                   // 512 slots / 64 lanes
        const int u = s >> 8, n = s & 255;
        const int gt  = r0 * TPR + 2 * g + u;
        const int gi  = (n < 255) ? (gt * N_NODE + 2 * n + 1) : (gt * N_NODE);
        const int gi2 = (n < 255) ? (gi + 1) : gi;
        thLr[j] = threshold[gi];
        thRr[j] = (n < 255) ? threshold[gi2] : 0.f;
        const int fa = feature[gi] & 255, fb = feature[gi2] & 255;
        fpr[j] = (n < 255) ? (fa | (fb << 8)) : fa;
    }

    // ---- stage x chunk transposed into LDS (conflict-free via XOR-swizzled R) ----
    {
        const float4* x4 = (const float4*)x;
        float4* R = (float4*)recbuf;                // 16 KB alias (pre-round-r0 only)
        #pragma unroll
        for (int rr = 0; rr < 2; ++rr) {
            #pragma unroll
            for (int k = 0; k < 4; ++k) {
                const int j  = tid + k * BLOCK;
                const int bl = j >> 5, f4 = j & 31;
                const int gb = chunk * BPB + rr * 32 + bl;
                float4 v = (gb < N_BATCH) ? x4[(size_t)gb * 32 + f4]
                                          : make_float4(0.f, 0.f, 0.f, 0.f);
                R[bl * 32 + (f4 ^ bl)] = v;
            }
            __syncthreads();
            {
                const int b32 = tid & 31, fc = tid >> 5;
                const int bb = rr * 32 + b32;
                #pragma unroll
                for (int c = 0; c < 4; ++c) {
                    const int f4 = fc * 4 + c;
                    float4 v = R[b32 * 32 + (f4 ^ b32)];
                    xt[(f4 * 4 + 0) * BPB + bb] = v.x;
                    xt[(f4 * 4 + 1) * BPB + bb] = v.y;
                    xt[(f4 * 4 + 2) * BPB + bb] = v.z;
                    xt[(f4 * 4 + 3) * BPB + bb] = v.w;
                }
            }
            __syncthreads();
        }
    }
    // From here: no block barriers until the final reduction; each wave owns
    // wbuf exclusively, ordered by its own lgkmcnt waits.

    float acc[N_OUTPUT];
    #pragma unroll
    for (int o = 0; o < N_OUTPUT; ++o) acc[o] = 0.f;

    float2*         pairT0 = (float2*)(wbuf);
    unsigned short* fp0    = (unsigned short*)(wbuf + 2048);
    float2*         pairT1 = (float2*)(wbuf + TREE_B);
    unsigned short* fp1    = (unsigned short*)(wbuf + TREE_B + 2048);

    for (int r = r0; r < r1; ++r) {
        __asm__ volatile("s_waitcnt lgkmcnt(0)" ::: "memory");   // WAR on wbuf
        #pragma unroll
        for (int j = 0; j < 8; ++j) {               // regs -> own LDS partition
            const int s = b + j * 64;
            const int u = s >> 8, n = s & 255;
            char* tb = wbuf + u * TREE_B;
            ((float2*)tb)[n] = make_float2(thLr[j], thRr[j]);
            ((unsigned short*)(tb + 2048))[n] = (unsigned short)fpr[j];
        }
        __asm__ volatile("s_waitcnt lgkmcnt(0)" ::: "memory");   // RAW visibility

        if (r + 1 < r1) {                           // prefetch next round
            #pragma unroll
            for (int j = 0; j < 8; ++j) {
                const int s = b + j * 64;
                const int u = s >> 8, n = s & 255;
                const int gt  = (r + 1) * TPR + 2 * g + u;
                const int gi  = (n < 255) ? (gt * N_NODE + 2 * n + 1) : (gt * N_NODE);
                const int gi2 = (n < 255) ? (gi + 1) : gi;
                thLr[j] = threshold[gi];
                thRr[j] = (n < 255) ? threshold[gi2] : 0.f;
                const int fa = feature[gi] & 255, fb = feature[gi2] & 255;
                fpr[j] = (n < 255) ? (fa | (fb << 8)) : fa;
            }
        }

        // ---- traverse 2 trees; next record selected from regs (1 LDS lat/level) ----
        int n0 = 0, n1 = 0;
        float th0 = pairT0[255].x, th1 = pairT1[255].x;    // roots
        int   fv0 = fp0[255] & 255, fv1 = fp1[255] & 255;
        float2 c0 = pairT0[0], c1 = pairT1[0];             // children of root
        int   k0 = fp0[0], k1 = fp1[0];
        #pragma unroll
        for (int d = 0; d < DEPTH; ++d) {
            const float xv0 = xt[fv0 * BPB + b];           // only on-chain LDS read
            const float xv1 = xt[fv1 * BPB + b];
            const int s0 = (xv0 > th0) ? 1 : 0;            // xval <= split -> left
            const int s1 = (xv1 > th1) ? 1 : 0;
            n0 = 2 * n0 + 1 + s0;
            n1 = 2 * n1 + 1 + s1;
            if (d < DEPTH - 1) {
                th0 = s0 ? c0.y : c0.x;  fv0 = (k0 >> (s0 << 3)) & 255;
                th1 = s1 ? c1.y : c1.x;  fv1 = (k1 >> (s1 << 3)) & 255;
            }
            if (d < DEPTH - 2) {                           // speculative pair read (n <= 254)
                c0 = pairT0[n0]; k0 = fp0[n0];
                c1 = pairT1[n1]; k1 = fp1[n1];
            }
        }
        {
            const int gt0 = r * TPR + 2 * g;
            const float4* v0 = (const float4*)(value + ((size_t)gt0 * N_NODE + n0) * N_OUTPUT);
            const float4* v1 = (const float4*)(value + ((size_t)(gt0 + 1) * N_NODE + n1) * N_OUTPUT);
            const float4 a0 = v0[0], a1 = v0[1];
            const float4 d0 = v1[0], d1 = v1[1];
            acc[0] += a0.x + d0.x;  acc[1] += a0.y + d0.y;
            acc[2] += a0.z + d0.z;  acc[3] += a0.w + d0.w;
            acc[4] += a1.x + d1.x;  acc[5] += a1.y + d1.y;
            acc[6] += a1.z + d1.z;  acc[7] += a1.w + d1.w;
        }
    }

    // ---- reduce 4 waves' partials (alias recbuf, stride-9 pad) ----
    __syncthreads();
    float* red = (float*)recbuf;                    // 4*576*4 = 9216 B <= 20480
    {
        float* dst = red + (g * 576 + b * 9);
        #pragma unroll
        for (int o = 0; o < N_OUTPUT; ++o) dst[o] = acc[o];
    }
    __syncthreads();
    {
        const int bl = tid >> 2, o0 = (tid & 3) * 2;
        const int bg = chunk * BPB + bl;
        if (bg < N_BATCH) {
            float s0 = 0.f, s1 = 0.f;
            #pragma unroll
            for (int gg = 0; gg < 4; ++gg) {
                s0 += red[gg * 576 + bl * 9 + o0];
                s1 += red[gg * 576 + bl * 9 + o0 + 1];
            }
            if (!tail) {
                float2 res;
                res.x = s0 * (1.0f / N_TREE);
                res.y = s1 * (1.0f / N_TREE);
                ((float2*)out)[(size_t)chunk * 256 + tid] = res;   // exactly once
            } else {
                atomicAdd(out + (size_t)bg * N_OUTPUT + o0,     s0 * (1.0f / N_TREE));
                atomicAdd(out + (size_t)bg * N_OUTPUT + o0 + 1, s1 * (1.0f / N_TREE));
            }
        }
    }
}

extern "C" void kernel_launch(void* const* d_in, const int* in_sizes, int n_in,
                              void* d_out, int out_size, void* d_ws, size_t ws_size,
                              hipStream_t stream) {
    const float* x         = (const float*)d_in[0];
    const int*   feature   = (const int*)d_in[1];
    const float* threshold = (const float*)d_in[2];
    const float* value     = (const float*)d_in[5];   // children implied by complete heap layout
    float* out = (float*)d_out;

    // zero only the tail-chunk region (atomic accumulation); 27 KB
    const size_t tail_off = (size_t)FULL_CHUNKS * BPB * N_OUTPUT;
    if ((size_t)out_size > tail_off) {
        hipMemsetAsync(out + tail_off, 0, ((size_t)out_size - tail_off) * sizeof(float), stream);
    }

    tree_kernel<<<dim3(GRID), dim3(BLOCK), 0, stream>>>(x, feature, threshold, value, out);
}

// Round 8
// 138.698 us; speedup vs baseline: 2.1353x; 1.1556x over previous
//
#include <hip/hip_runtime.h>

#define N_BATCH   50000
#define N_FEATURE 128
#define DEPTH     9
#define N_TREE    200
#define N_NODE    1023
#define N_OUTPUT  8

#define BPB     64                            // batches per block (lanes)
#define BLOCK   256                           // 4 waves
#define TPR     8                             // trees per round (2 per wave)
#define ROUNDS  (N_TREE / TPR)                // 25

// Grid: 768 monolithic chunk-blocks (one clean 3/CU phase) + 14 surplus chunks
// shattered into 25 single-round blocks that backfill draining slots.
#define FULL_CHUNKS 768
#define NCHUNK      ((N_BATCH + BPB - 1) / BPB)     // 782
#define TAIL_CHUNKS (NCHUNK - FULL_CHUNKS)          // 14
#define TAIL_SPLIT  ROUNDS
#define TAIL_BLOCKS (TAIL_CHUNKS * TAIL_SPLIT)      // 350
#define GRID        (FULL_CHUNKS + TAIL_BLOCKS)     // 1118

// Per-wave private record buffer. KEY IDENTITY: the child-pair layout
// (th[2n+1], th[2n+2]) indexed by parent n is the heap array shifted by 1:
//   flatTh[k] = th[k+1]  (k = 0..509 internal children; slot 511 = root th)
//   fS[k]     = feat[k+1] as u8       (byte 511 = root feat)
// pair(n) = ds_read_b64 @ 8n (aligned), fpair(n) = ds_read_u16 @ 2n (aligned).
// Staging is therefore a plain coalesced shifted copy of the INTERNAL half
// of each tree's arrays (2KB th + 0.5KB f), not a repack.
#define TREE_B  2560                          // 512*4 th + 512 u8 f
#define WAVE_B  (2 * TREE_B)                  // 5120
#define REC_B   (4 * WAVE_B)                  // 20480

__global__ __launch_bounds__(BLOCK, 3)
void tree_kernel(const float* __restrict__ x,
                 const int*   __restrict__ feature,
                 const float* __restrict__ threshold,
                 const float* __restrict__ value,
                 float*       __restrict__ out)
{
    __shared__ float xt[N_FEATURE * BPB];           // 32 KB, xt[f*64+b]: bank = lane%32 (free)
    __shared__ __align__(16) char recbuf[REC_B];    // 20 KB, partitioned per wave

    const int tid = threadIdx.x;
    const int bid = blockIdx.x;
    const int b   = tid & 63;
    const int g   = tid >> 6;
    char* wbuf = recbuf + g * WAVE_B;

    int chunk, r0, r1; bool tail;
    if (bid < FULL_CHUNKS) { chunk = bid; r0 = 0; r1 = ROUNDS; tail = false; }
    else {
        const int t2 = bid - FULL_CHUNKS;
        chunk = FULL_CHUNKS + t2 / TAIL_SPLIT;
        r0 = t2 % TAIL_SPLIT; r1 = r0 + 1; tail = true;
    }

    // ---- prefetch round-r0 records: dense coalesced loads of s=0..511 ----
    float thr[2][8]; int fr[2][8];
    #pragma unroll
    for (int u = 0; u < 2; ++u) {
        const int base = (r0 * TPR + 2 * g + u) * N_NODE;
        #pragma unroll
        for (int j = 0; j < 8; ++j) {
            const int s = b + j * 64;
            thr[u][j] = threshold[base + s];
            fr[u][j]  = feature[base + s];
        }
    }

    // ---- stage x chunk transposed into LDS (conflict-free via XOR-swizzled R) ----
    {
        const float4* x4 = (const float4*)x;
        float4* R = (float4*)recbuf;                // alias, pre-round only
        #pragma unroll
        for (int rr = 0; rr < 2; ++rr) {
            #pragma unroll
            for (int k = 0; k < 4; ++k) {
                const int j  = tid + k * BLOCK;
                const int bl = j >> 5, f4 = j & 31;
                const int gb = chunk * BPB + rr * 32 + bl;
                float4 v = (gb < N_BATCH) ? x4[(size_t)gb * 32 + f4]
                                          : make_float4(0.f, 0.f, 0.f, 0.f);
                R[bl * 32 + (f4 ^ bl)] = v;
            }
            __syncthreads();
            {
                const int b32 = tid & 31, fc = tid >> 5;
                const int bb = rr * 32 + b32;
                #pragma unroll
                for (int c = 0; c < 4; ++c) {
                    const int f4 = fc * 4 + c;
                    float4 v = R[b32 * 32 + (f4 ^ b32)];
                    xt[(f4 * 4 + 0) * BPB + bb] = v.x;
                    xt[(f4 * 4 + 1) * BPB + bb] = v.y;
                    xt[(f4 * 4 + 2) * BPB + bb] = v.z;
                    xt[(f4 * 4 + 3) * BPB + bb] = v.w;
                }
            }
            __syncthreads();
        }
    }
    // No block barriers from here until the final reduction: each wave owns
    // wbuf exclusively, ordered by its own lgkmcnt waits.

    float acc[N_OUTPUT];
    #pragma unroll
    for (int o = 0; o < N_OUTPUT; ++o) acc[o] = 0.f;

    float*          tb0f = (float*)wbuf;
    unsigned char*  fb0  = (unsigned char*)(wbuf + 2048);
    float*          tb1f = (float*)(wbuf + TREE_B);
    unsigned char*  fb1  = (unsigned char*)(wbuf + TREE_B + 2048);

    for (int r = r0; r < r1; ++r) {
        __asm__ volatile("s_waitcnt lgkmcnt(0)" ::: "memory");   // WAR on wbuf
        #pragma unroll
        for (int u = 0; u < 2; ++u) {                // shifted copy: dst = s-1 (root -> 511)
            char* tb = wbuf + u * TREE_B;
            #pragma unroll
            for (int j = 0; j < 8; ++j) {
                const int s   = b + j * 64;
                const int dst = (s == 0) ? 511 : s - 1;
                ((float*)tb)[dst] = thr[u][j];
                ((unsigned char*)(tb + 2048))[dst] = (unsigned char)fr[u][j];
            }
        }
        __asm__ volatile("s_waitcnt lgkmcnt(0)" ::: "memory");   // RAW visibility

        if (r + 1 < r1) {                            // dense coalesced prefetch of next round
            #pragma unroll
            for (int u = 0; u < 2; ++u) {
                const int base = ((r + 1) * TPR + 2 * g + u) * N_NODE;
                #pragma unroll
                for (int j = 0; j < 8; ++j) {
                    const int s = b + j * 64;
                    thr[u][j] = threshold[base + s];
                    fr[u][j]  = feature[base + s];
                }
            }
        }

        // ---- traverse 2 trees; next record selected from regs (1 LDS lat/level) ----
        int n0 = 0, n1 = 0;
        float th0 = tb0f[511], th1 = tb1f[511];      // roots
        int   fv0 = fb0[511],  fv1 = fb1[511];
        float2 c0 = ((float2*)tb0f)[0], c1 = ((float2*)tb1f)[0];   // children of root
        int   k0 = ((unsigned short*)fb0)[0], k1 = ((unsigned short*)fb1)[0];
        #pragma unroll
        for (int d = 0; d < DEPTH; ++d) {
            const float xv0 = xt[fv0 * BPB + b];     // only on-chain LDS read
            const float xv1 = xt[fv1 * BPB + b];
            const int s0 = (xv0 > th0) ? 1 : 0;      // xval <= split -> left
            const int s1 = (xv1 > th1) ? 1 : 0;
            n0 = 2 * n0 + 1 + s0;
            n1 = 2 * n1 + 1 + s1;
            if (d < DEPTH - 1) {
                th0 = s0 ? c0.y : c0.x;  fv0 = (k0 >> (s0 << 3)) & 255;
                th1 = s1 ? c1.y : c1.x;  fv1 = (k1 >> (s1 << 3)) & 255;
            }
            if (d < DEPTH - 2) {                     // speculative pair read (n <= 254)
                c0 = ((float2*)tb0f)[n0]; k0 = ((unsigned short*)fb0)[n0];
                c1 = ((float2*)tb1f)[n1]; k1 = ((unsigned short*)fb1)[n1];
            }
        }
        {
            const int gt0 = r * TPR + 2 * g;
            const float4* v0 = (const float4*)(value + ((size_t)gt0 * N_NODE + n0) * N_OUTPUT);
            const float4* v1 = (const float4*)(value + ((size_t)(gt0 + 1) * N_NODE + n1) * N_OUTPUT);
            const float4 a0 = v0[0], a1 = v0[1];
            const float4 d0 = v1[0], d1 = v1[1];
            acc[0] += a0.x + d0.x;  acc[1] += a0.y + d0.y;
            acc[2] += a0.z + d0.z;  acc[3] += a0.w + d0.w;
            acc[4] += a1.x + d1.x;  acc[5] += a1.y + d1.y;
            acc[6] += a1.z + d1.z;  acc[7] += a1.w + d1.w;
        }
    }

    // ---- reduce 4 waves' partials (alias recbuf, stride-9 pad) ----
    __syncthreads();
    float* red = (float*)recbuf;                    // 9216 B <= 20480
    {
        float* dst = red + (g * 576 + b * 9);
        #pragma unroll
        for (int o = 0; o < N_OUTPUT; ++o) dst[o] = acc[o];
    }
    __syncthreads();
    {
        const int bl = tid >> 2, o0 = (tid & 3) * 2;
        const int bg = chunk * BPB + bl;
        if (bg < N_BATCH) {
            float s0 = 0.f, s1 = 0.f;
            #pragma unroll
            for (int gg = 0; gg < 4; ++gg) {
                s0 += red[gg * 576 + bl * 9 + o0];
                s1 += red[gg * 576 + bl * 9 + o0 + 1];
            }
            if (!tail) {
                float2 res;
                res.x = s0 * (1.0f / N_TREE);
                res.y = s1 * (1.0f / N_TREE);
                ((float2*)out)[(size_t)chunk * 256 + tid] = res;   // exactly once
            } else {
                atomicAdd(out + (size_t)bg * N_OUTPUT + o0,     s0 * (1.0f / N_TREE));
                atomicAdd(out + (size_t)bg * N_OUTPUT + o0 + 1, s1 * (1.0f / N_TREE));
            }
        }
    }
}

extern "C" void kernel_launch(void* const* d_in, const int* in_sizes, int n_in,
                              void* d_out, int out_size, void* d_ws, size_t ws_size,
                              hipStream_t stream) {
    const float* x         = (const float*)d_in[0];
    const int*   feature   = (const int*)d_in[1];
    const float* threshold = (const float*)d_in[2];
    const float* value     = (const float*)d_in[5];   // children implied by complete heap layout
    float* out = (float*)d_out;

    // zero only the tail-chunk region (atomic accumulation); ~27 KB
    const size_t tail_off = (size_t)FULL_CHUNKS * BPB * N_OUTPUT;
    if ((size_t)out_size > tail_off) {
        hipMemsetAsync(out + tail_off, 0, ((size_t)out_size - tail_off) * sizeof(float), stream);
    }

    tree_kernel<<<dim3(GRID), dim3(BLOCK), 0, stream>>>(x, feature, threshold, value, out);
}

// Round 9
// 135.180 us; speedup vs baseline: 2.1909x; 1.0260x over previous
//
#include <hip/hip_runtime.h>

#define N_BATCH   50000
#define N_FEATURE 128
#define DEPTH     9
#define N_TREE    200
#define N_NODE    1023
#define N_OUTPUT  8

#define BPB     64                            // batches per block (lanes)
#define WAVES   8
#define BLOCK   (WAVES * 64)                  // 512 threads
#define TPR     8                             // trees per round (1 per wave)
#define ROUNDS  (N_TREE / TPR)                // 25

// Grid: 768 monolithic chunk-blocks (3/CU x 256 CU, one clean phase) + 14
// surplus chunks shattered into 25 single-round blocks that backfill.
#define FULL_CHUNKS 768
#define NCHUNK      ((N_BATCH + BPB - 1) / BPB)     // 782
#define TAIL_CHUNKS (NCHUNK - FULL_CHUNKS)          // 14
#define TAIL_SPLIT  ROUNDS
#define TAIL_BLOCKS (TAIL_CHUNKS * TAIL_SPLIT)      // 350
#define GRID        (FULL_CHUNKS + TAIL_BLOCKS)     // 1118

// Per-wave private buffer, 1 tree: shifted heap copy
//   thS[k] = th[k+1] (k=0..510), thS[511] = th[0] (root)   [2048 B]
//   fS[k]  = feat[k+1] u8,       fS[511]  = root feat      [512 B]
// pair(n) = float2 @ thS[2n] (8B aligned), fpair(n) = u16 @ fS[2n].
#define TREE_B  2560
#define REC_B   (WAVES * TREE_B)              // 20480

__global__ __launch_bounds__(BLOCK, 6)        // 6 waves/EU -> 3 blocks/CU, 24 waves/CU
void tree_kernel(const float* __restrict__ x,
                 const int*   __restrict__ feature,
                 const float* __restrict__ threshold,
                 const float* __restrict__ value,
                 float*       __restrict__ out)
{
    __shared__ float xt[N_FEATURE * BPB];           // 32 KB, xt[f*64+b]: bank = lane%32 (free)
    __shared__ __align__(16) char recbuf[REC_B];    // 20 KB, 8 wave-private 2560B slices

    const int tid = threadIdx.x;
    const int bid = blockIdx.x;
    const int b   = tid & 63;                       // lane = batch within chunk
    const int g   = tid >> 6;                       // wave id: tree g of each round
    char* wbuf = recbuf + g * TREE_B;

    int chunk, r0, r1; bool tail;
    if (bid < FULL_CHUNKS) { chunk = bid; r0 = 0; r1 = ROUNDS; tail = false; }
    else {
        const int t2 = bid - FULL_CHUNKS;
        chunk = FULL_CHUNKS + t2 / TAIL_SPLIT;
        r0 = t2 % TAIL_SPLIT; r1 = r0 + 1; tail = true;
    }

    // incremental per-round bases (avoid 64-bit muls in the loop)
    const float* tpre = threshold + (size_t)(r0 * TPR + g) * N_NODE + b;
    const int*   fpre = feature   + (size_t)(r0 * TPR + g) * N_NODE + b;
    const float* vbase = value + (size_t)(r0 * TPR + g) * N_NODE * N_OUTPUT;

    // ---- prefetch round-r0 records (dense coalesced, imm-offset friendly) ----
    float thr[8]; int fr[8];
    #pragma unroll
    for (int j = 0; j < 8; ++j) { thr[j] = tpre[j * 64]; fr[j] = fpre[j * 64]; }

    // ---- stage x chunk transposed into LDS (conflict-free via XOR-swizzled R) ----
    {
        const float4* x4 = (const float4*)x;
        float4* R = (float4*)recbuf;                // 16 KB alias (pre-round only)
        #pragma unroll
        for (int rr = 0; rr < 2; ++rr) {
            #pragma unroll
            for (int k = 0; k < 2; ++k) {           // 1024 float4 / 512 thr = 2 iters
                const int j  = tid + k * BLOCK;
                const int bl = j >> 5, f4 = j & 31;
                const int gb = chunk * BPB + rr * 32 + bl;
                float4 v = (gb < N_BATCH) ? x4[(size_t)gb * 32 + f4]
                                          : make_float4(0.f, 0.f, 0.f, 0.f);
                R[bl * 32 + (f4 ^ bl)] = v;
            }
            __syncthreads();
            {
                const int b32 = tid & 31, fc = tid >> 5;   // fc = 0..15
                const int bb = rr * 32 + b32;
                #pragma unroll
                for (int c = 0; c < 2; ++c) {
                    const int f4 = fc * 2 + c;
                    float4 v = R[b32 * 32 + (f4 ^ b32)];
                    xt[(f4 * 4 + 0) * BPB + bb] = v.x;
                    xt[(f4 * 4 + 1) * BPB + bb] = v.y;
                    xt[(f4 * 4 + 2) * BPB + bb] = v.z;
                    xt[(f4 * 4 + 3) * BPB + bb] = v.w;
                }
            }
            __syncthreads();
        }
    }
    // No block barriers from here until the final reduction: each wave owns
    // wbuf exclusively, ordered by its own lgkmcnt waits.

    float acc[N_OUTPUT];
    #pragma unroll
    for (int o = 0; o < N_OUTPUT; ++o) acc[o] = 0.f;

    float*         thS = (float*)wbuf;
    unsigned char* fS  = (unsigned char*)(wbuf + 2048);

    for (int r = r0; r < r1; ++r) {
        __asm__ volatile("s_waitcnt lgkmcnt(0)" ::: "memory");   // WAR on wbuf
        #pragma unroll
        for (int j = 0; j < 8; ++j) {               // shifted copy, branchless dst
            const int dst = (b + j * 64 - 1) & 511; // s=0 -> 511 (root)
            thS[dst] = thr[j];
            fS[dst]  = (unsigned char)fr[j];
        }
        __asm__ volatile("s_waitcnt lgkmcnt(0)" ::: "memory");   // RAW visibility

        if (r + 1 < r1) {                           // dense coalesced prefetch, next round
            const float* tn = tpre + TPR * N_NODE;
            const int*   fn = fpre + TPR * N_NODE;
            #pragma unroll
            for (int j = 0; j < 8; ++j) { thr[j] = tn[j * 64]; fr[j] = fn[j * 64]; }
            tpre = tn; fpre = fn;
        }

        // ---- traverse 1 tree; next record selected from regs (1 LDS lat/level) ----
        int n = 0;
        float th = thS[511];                        // root
        int   fv = fS[511];
        float2 c = ((float2*)thS)[0];               // children of root
        int   k  = ((unsigned short*)fS)[0];
        #pragma unroll
        for (int d = 0; d < DEPTH; ++d) {
            const float xv = xt[fv * BPB + b];      // only on-chain LDS read
            const int s = (xv > th) ? 1 : 0;        // xval <= split -> left
            n = 2 * n + 1 + s;
            if (d < DEPTH - 1) {
                th = s ? c.y : c.x;
                fv = (k >> (s << 3)) & 255;
            }
            if (d < DEPTH - 2) {                    // speculative pair read (n <= 254)
                c = ((float2*)thS)[n];
                k = ((unsigned short*)fS)[n];
            }
        }
        {
            const float4* vp = (const float4*)(vbase + (size_t)n * N_OUTPUT);
            const float4 a0 = vp[0], a1 = vp[1];
            acc[0] += a0.x; acc[1] += a0.y; acc[2] += a0.z; acc[3] += a0.w;
            acc[4] += a1.x; acc[5] += a1.y; acc[6] += a1.z; acc[7] += a1.w;
        }
        vbase += (size_t)TPR * N_NODE * N_OUTPUT;
    }

    // ---- reduce 8 waves' partials (alias recbuf, stride-9 pad) ----
    __syncthreads();
    float* red = (float*)recbuf;                    // 8*576*4 = 18432 <= 20480
    {
        float* dst = red + (g * 576 + b * 9);
        #pragma unroll
        for (int o = 0; o < N_OUTPUT; ++o) dst[o] = acc[o];
    }
    __syncthreads();
    {
        const int bl = tid >> 3, o = tid & 7;       // 512 threads = 64 batches x 8 outs
        const int bg = chunk * BPB + bl;
        float s = 0.f;
        #pragma unroll
        for (int gg = 0; gg < WAVES; ++gg) s += red[gg * 576 + bl * 9 + o];
        s *= (1.0f / N_TREE);
        if (!tail) {
            out[(size_t)chunk * (BPB * N_OUTPUT) + tid] = s;   // coalesced, exactly once
        } else if (bg < N_BATCH) {
            atomicAdd(out + (size_t)bg * N_OUTPUT + o, s);
        }
    }
}

extern "C" void kernel_launch(void* const* d_in, const int* in_sizes, int n_in,
                              void* d_out, int out_size, void* d_ws, size_t ws_size,
                              hipStream_t stream) {
    const float* x         = (const float*)d_in[0];
    const int*   feature   = (const int*)d_in[1];
    const float* threshold = (const float*)d_in[2];
    const float* value     = (const float*)d_in[5];   // children implied by complete heap layout
    float* out = (float*)d_out;

    // zero only the tail-chunk region (atomic accumulation); ~27 KB
    const size_t tail_off = (size_t)FULL_CHUNKS * BPB * N_OUTPUT;
    if ((size_t)out_size > tail_off) {
        hipMemsetAsync(out + tail_off, 0, ((size_t)out_size - tail_off) * sizeof(float), stream);
    }

    tree_kernel<<<dim3(GRID), dim3(BLOCK), 0, stream>>>(x, feature, threshold, value, out);
}